// Round 1
// baseline (738.040 us; speedup 1.0000x reference)
//
#include <hip/hip_runtime.h>
#include <cstdint>

#define AS1 __attribute__((address_space(1)))
#define AS3 __attribute__((address_space(3)))

typedef __bf16 bf16x8 __attribute__((ext_vector_type(8)));
typedef __bf16 bf16x4 __attribute__((ext_vector_type(4)));
typedef float  f32x4  __attribute__((ext_vector_type(4)));

// ---------------------------------------------------------------------------
// Elementwise / transpose kernels
// ---------------------------------------------------------------------------

// Copy input [B][1024][4096] fp32 into top half of out [B][2048][4096]
__global__ void copy_in_k(const float4* __restrict__ in, float4* __restrict__ out) {
  int i = blockIdx.x * 256 + threadIdx.x;       // total 4*1024*4096/4 = 4194304
  int b = i >> 20;                              // 1048576 float4 per batch slice
  int r = i & 1048575;
  out[(long)b * 2097152 + r] = in[i];
}

// input slice [1024][4096] fp32 -> xb [4096][1024] bf16 (tiled transpose)
__global__ void transpose_x_k(const float* __restrict__ in, __bf16* __restrict__ out) {
  __shared__ float t[32][33];
  int s0 = blockIdx.x * 32, c0 = blockIdx.y * 32;
  int tx = threadIdx.x, ty = threadIdx.y;
#pragma unroll
  for (int i = 0; i < 4; i++)
    t[ty + i * 8][tx] = in[(c0 + ty + i * 8) * 4096 + s0 + tx];
  __syncthreads();
#pragma unroll
  for (int i = 0; i < 4; i++)
    out[(s0 + ty + i * 8) * 1024 + c0 + tx] = (__bf16)t[tx][ty + i * 8];
}

// Wq/Wk/Wv [1024][1024] fp32 -> Wt [3072][1024] bf16, transposed ([n][c]),
// with 1/sqrt(K)=1/32 folded into the Q slice.
__global__ void transpose_w_k(const float* __restrict__ Wq, const float* __restrict__ Wk,
                              const float* __restrict__ Wv, __bf16* __restrict__ Wt) {
  __shared__ float t[32][33];
  int sel = blockIdx.z;
  const float* W = sel == 0 ? Wq : (sel == 1 ? Wk : Wv);
  float scale = sel == 0 ? 0.03125f : 1.0f;
  int n0 = blockIdx.x * 32, c0 = blockIdx.y * 32;
  int tx = threadIdx.x, ty = threadIdx.y;
#pragma unroll
  for (int i = 0; i < 4; i++)
    t[ty + i * 8][tx] = W[(c0 + ty + i * 8) * 1024 + n0 + tx];
  __syncthreads();
#pragma unroll
  for (int i = 0; i < 4; i++)
    Wt[(sel * 1024 + n0 + ty + i * 8) * 1024 + c0 + tx] = (__bf16)(t[tx][ty + i * 8] * scale);
}

__global__ void bcat_k(const float* __restrict__ bq, const float* __restrict__ bk,
                       const float* __restrict__ bv, float* __restrict__ bcat) {
  int n = blockIdx.x * 256 + threadIdx.x;       // 3072 total
  float v = n < 1024 ? bq[n] * 0.03125f : (n < 2048 ? bk[n - 1024] : bv[n - 2048]);
  bcat[n] = v;
}

// ---------------------------------------------------------------------------
// 128x128 bf16 MFMA GEMM core (m97 structure): BK=32, 256 threads = 4 waves
// in 2x2, each wave 4x4 fragments of 16x16x32. A row-major [M][K], B as
// B^T row-major [N][K]. acc[m][n] = sum_k A[m,k]*B[n,k].
// ---------------------------------------------------------------------------
__device__ __forceinline__ void gemm128_core(const __bf16* __restrict__ A, int lda, int m0,
                                             const __bf16* __restrict__ B, int ldb, int n0,
                                             int Klen, __bf16* As, __bf16* Bs,
                                             f32x4 acc[4][4]) {
  const int tid = threadIdx.x;
  const int lane = tid & 63;
  const int wid = tid >> 6;
  const int wr = wid >> 1, wc = wid & 1;
  const int lr = lane & 15;
  const int lk = (lane >> 4) << 3;
  const int srow = tid >> 2;            // 0..63
  const int skq = (tid & 3) << 3;       // 0,8,16,24
  const __bf16* ga = A + (long)(m0 + srow) * lda + skq;
  const __bf16* gb = B + (long)(n0 + srow) * ldb + skq;

  for (int k0 = 0; k0 < Klen; k0 += 32) {
    __builtin_amdgcn_global_load_lds((const AS1 void*)(ga + k0),            (AS3 void*)(As + tid * 8),        16, 0, 0);
    __builtin_amdgcn_global_load_lds((const AS1 void*)(ga + k0 + 64 * lda), (AS3 void*)(As + tid * 8 + 2048), 16, 0, 0);
    __builtin_amdgcn_global_load_lds((const AS1 void*)(gb + k0),            (AS3 void*)(Bs + tid * 8),        16, 0, 0);
    __builtin_amdgcn_global_load_lds((const AS1 void*)(gb + k0 + 64 * ldb), (AS3 void*)(Bs + tid * 8 + 2048), 16, 0, 0);
    __syncthreads();
    bf16x8 af[4], bfr[4];
#pragma unroll
    for (int m = 0; m < 4; m++)
      af[m] = *(const bf16x8*)(As + (wr * 64 + m * 16 + lr) * 32 + lk);
#pragma unroll
    for (int n = 0; n < 4; n++)
      bfr[n] = *(const bf16x8*)(Bs + (wc * 64 + n * 16 + lr) * 32 + lk);
#pragma unroll
    for (int m = 0; m < 4; m++)
#pragma unroll
      for (int n = 0; n < 4; n++)
        acc[m][n] = __builtin_amdgcn_mfma_f32_16x16x32_bf16(af[m], bfr[n], acc[m][n], 0, 0, 0);
    __syncthreads();
  }
}

// ---------------------------------------------------------------------------
// QKV fused projection: [4096 x 3072] = xb[4096x1024] @ Wt^T
// n<1024 -> Q (pre-scaled 1/32), n<2048 -> K, else V stored transposed [v][s]
// ---------------------------------------------------------------------------
__global__ void qkv_gemm_k(const __bf16* __restrict__ xb, const __bf16* __restrict__ Wt,
                           const float* __restrict__ bcat, __bf16* __restrict__ Qb,
                           __bf16* __restrict__ Kb, __bf16* __restrict__ Vt) {
  __shared__ __bf16 As[4096], Bs[4096];
  f32x4 acc[4][4] = {};
  int m0 = blockIdx.y * 128, n0 = blockIdx.x * 128;
  gemm128_core(xb, 1024, m0, Wt, 1024, n0, 1024, As, Bs, acc);

  const int lane = threadIdx.x & 63;
  const int wid = threadIdx.x >> 6;
  const int wr = wid >> 1, wc = wid & 1;
  const int lr = lane & 15;
  const int lg = (lane >> 4) * 4;
#pragma unroll
  for (int m = 0; m < 4; m++) {
    int rs = m0 + wr * 64 + m * 16 + lg;
#pragma unroll
    for (int n = 0; n < 4; n++) {
      int col = n0 + wc * 64 + n * 16 + lr;
      float bias = bcat[col];
      if (col < 1024) {
#pragma unroll
        for (int r = 0; r < 4; r++)
          Qb[(rs + r) * 1024 + col] = (__bf16)(acc[m][n][r] + bias);
      } else if (col < 2048) {
#pragma unroll
        for (int r = 0; r < 4; r++)
          Kb[(rs + r) * 1024 + (col - 1024)] = (__bf16)(acc[m][n][r] + bias);
      } else {
        bf16x4 t4;
#pragma unroll
        for (int r = 0; r < 4; r++) t4[r] = (__bf16)(acc[m][n][r] + bias);
        *(bf16x4*)(Vt + (long)(col - 2048) * 4096 + rs) = t4;
      }
    }
  }
}

// ---------------------------------------------------------------------------
// QK^T: scores[s][t] = Q[s,:]·K[t,:]  (Q pre-scaled by 1/32). Upper-tri tiles skipped.
// Score row stride = 4096 floats (16KB).
// ---------------------------------------------------------------------------
__global__ void qk_gemm_k(const __bf16* __restrict__ Qb, const __bf16* __restrict__ Kb,
                          float* __restrict__ sc) {
  if (blockIdx.x > blockIdx.y) return;  // tile fully above diagonal
  __shared__ __bf16 As[4096], Bs[4096];
  f32x4 acc[4][4] = {};
  int m0 = blockIdx.y * 128, n0 = blockIdx.x * 128;
  gemm128_core(Qb, 1024, m0, Kb, 1024, n0, 1024, As, Bs, acc);

  const int lane = threadIdx.x & 63;
  const int wid = threadIdx.x >> 6;
  const int wr = wid >> 1, wc = wid & 1;
  const int lr = lane & 15;
  const int lg = (lane >> 4) * 4;
#pragma unroll
  for (int m = 0; m < 4; m++) {
    int rs = m0 + wr * 64 + m * 16 + lg;
#pragma unroll
    for (int n = 0; n < 4; n++) {
      int col = n0 + wc * 64 + n * 16 + lr;
#pragma unroll
      for (int r = 0; r < 4; r++)
        sc[(long)(rs + r) * 4096 + col] = acc[m][n][r];
    }
  }
}

// ---------------------------------------------------------------------------
// Row softmax with causal mask + alibi. P (bf16, 4096 entries, zeros above
// diagonal) written IN PLACE into the second 8KB half of each 16KB score row.
// ---------------------------------------------------------------------------
__global__ void softmax_k(float* __restrict__ sc, const float* __restrict__ frame,
                          const float* __restrict__ alibi_p) {
  __shared__ float buf[4096];
  __shared__ float red[4];
  int s = blockIdx.x;
  float* srow = sc + (long)s * 4096;
  __bf16* prow = (__bf16*)(srow + 2048);
  int tid = threadIdx.x, lane = tid & 63, wid = tid >> 6;
  float sig = 1.0f / (1.0f + __expf(-alibi_p[0]));
  float fs = frame[s];
  int n = s + 1;

  float mx = -3.4e38f;
  for (int t = tid; t < n; t += 256) {
    float v = srow[t] - sig * fabsf(frame[t] - fs);
    buf[t] = v;
    mx = fmaxf(mx, v);
  }
#pragma unroll
  for (int o = 32; o; o >>= 1) mx = fmaxf(mx, __shfl_xor(mx, o, 64));
  if (lane == 0) red[wid] = mx;
  __syncthreads();
  mx = fmaxf(fmaxf(red[0], red[1]), fmaxf(red[2], red[3]));

  float sum = 0.0f;
  for (int t = tid; t < n; t += 256) {
    float e = __expf(buf[t] - mx);
    buf[t] = e;
    sum += e;
  }
#pragma unroll
  for (int o = 32; o; o >>= 1) sum += __shfl_xor(sum, o, 64);
  __syncthreads();
  if (lane == 0) red[wid] = sum;
  __syncthreads();
  sum = red[0] + red[1] + red[2] + red[3];
  float inv = 1.0f / sum;

  for (int t = tid; t < 4096; t += 256) {
    float p = (t < n) ? buf[t] * inv : 0.0f;
    prow[t] = (__bf16)p;
  }
}

// ---------------------------------------------------------------------------
// PV: out[v][s] (transposed into d_out) = sum_t P[s,t] * Vt[v,t], t < s0+128.
// P row stride = 8192 bf16 elements (16KB).
// ---------------------------------------------------------------------------
__global__ void pv_gemm_k(const __bf16* __restrict__ P, const __bf16* __restrict__ Vt,
                          float* __restrict__ outb) {
  __shared__ __bf16 As[4096], Bs[4096];
  f32x4 acc[4][4] = {};
  int m0 = blockIdx.y * 128, n0 = blockIdx.x * 128;
  int Klen = m0 + 128;  // causal bound (P is zero above diagonal within last tile)
  gemm128_core(P, 8192, m0, Vt, 4096, n0, Klen, As, Bs, acc);

  const int lane = threadIdx.x & 63;
  const int wid = threadIdx.x >> 6;
  const int wr = wid >> 1, wc = wid & 1;
  const int lr = lane & 15;
  const int lg = (lane >> 4) * 4;
#pragma unroll
  for (int m = 0; m < 4; m++) {
    int rs = m0 + wr * 64 + m * 16 + lg;
#pragma unroll
    for (int n = 0; n < 4; n++) {
      int col = n0 + wc * 64 + n * 16 + lr;   // v index
      *(f32x4*)(outb + (long)col * 4096 + rs) = acc[m][n];
    }
  }
}

// ---------------------------------------------------------------------------

static inline char* align256(char* p) {
  return (char*)(((uintptr_t)p + 255) & ~(uintptr_t)255);
}

extern "C" void kernel_launch(void* const* d_in, const int* in_sizes, int n_in,
                              void* d_out, int out_size, void* d_ws, size_t ws_size,
                              hipStream_t stream) {
  const float* input = (const float*)d_in[0];   // [4][1024][4096]
  const float* frame = (const float*)d_in[1];   // [4096]
  const float* Wq = (const float*)d_in[2];
  const float* bq = (const float*)d_in[3];
  const float* Wk = (const float*)d_in[4];
  const float* bk = (const float*)d_in[5];
  const float* Wv = (const float*)d_in[6];
  const float* bv = (const float*)d_in[7];
  const float* alibi = (const float*)d_in[8];
  float* out = (float*)d_out;                   // [4][2048][4096]

  char* p = (char*)d_ws;
  __bf16* Wt = (__bf16*)p;  p += (size_t)3072 * 1024 * 2;
  float* bcat = (float*)p;  p += 3072 * 4;       p = align256(p);
  __bf16* xb = (__bf16*)p;  p += (size_t)4096 * 1024 * 2;  p = align256(p);
  __bf16* Qb = (__bf16*)p;  p += (size_t)4096 * 1024 * 2;  p = align256(p);
  __bf16* Kb = (__bf16*)p;  p += (size_t)4096 * 1024 * 2;  p = align256(p);
  __bf16* Vt = (__bf16*)p;  p += (size_t)4096 * 1024 * 2;  p = align256(p);
  float* sc = (float*)p;    // [4096][4096] fp32, 67MB; P aliased into row second halves

  transpose_w_k<<<dim3(32, 32, 3), dim3(32, 8), 0, stream>>>(Wq, Wk, Wv, Wt);
  bcat_k<<<12, 256, 0, stream>>>(bq, bk, bv, bcat);
  copy_in_k<<<16384, 256, 0, stream>>>((const float4*)input, (float4*)out);

  for (int b = 0; b < 4; b++) {
    const float* inb = input + (size_t)b * 1024 * 4096;
    transpose_x_k<<<dim3(128, 32), dim3(32, 8), 0, stream>>>(inb, xb);
    qkv_gemm_k<<<dim3(24, 32), 256, 0, stream>>>(xb, Wt, bcat, Qb, Kb, Vt);
    qk_gemm_k<<<dim3(32, 32), 256, 0, stream>>>(Qb, Kb, sc);
    softmax_k<<<4096, 256, 0, stream>>>(sc, frame, alibi);
    pv_gemm_k<<<dim3(8, 32), 256, 0, stream>>>((const __bf16*)((char*)sc + 8192), Vt,
                                               out + ((size_t)b * 2048 + 1024) * 4096);
  }
}